// Round 1
// baseline (1010.000 us; speedup 1.0000x reference)
//
#include <hip/hip_runtime.h>
#include <math.h>

#define NNODES 100000
#define NEDGES 1200000
#define HD 64
#define NLAYERS 8
#define NGRAPH 100

// ---------- order-preserving float<->uint encoding for atomicMax ----------
__device__ __forceinline__ unsigned enc_f(float f) {
    unsigned b = __float_as_uint(f);
    return (b & 0x80000000u) ? ~b : (b | 0x80000000u);
}
__device__ __forceinline__ float dec_f(unsigned u) {
    unsigned b = (u & 0x80000000u) ? (u ^ 0x80000000u) : ~u;
    return __uint_as_float(b);
}
// sentinel = enc(-inf) = 0x007FFFFF

// ---------- lin0: x0 = relu(pos @ lin0_w + lin0_b) ----------
__global__ void lin0_k(const float* __restrict__ pos, const float* __restrict__ w,
                       const float* __restrict__ b, float* __restrict__ x0, int total) {
    int i = blockIdx.x * blockDim.x + threadIdx.x;
    if (i >= total) return;
    int n = i >> 6, h = i & 63;
    float p0 = pos[n * 3 + 0], p1 = pos[n * 3 + 1], p2 = pos[n * 3 + 2];
    float v = fmaf(p0, w[h], fmaf(p1, w[64 + h], fmaf(p2, w[128 + h], b[h])));
    x0[i] = fmaxf(v, 0.0f);
}

// ---------- CSR build ----------
__global__ void hist_k(const int* __restrict__ dst, int* __restrict__ deg, int E) {
    int e = blockIdx.x * blockDim.x + threadIdx.x;
    if (e < E) atomicAdd(&deg[dst[e]], 1);
}

__global__ void scan_part_k(const int* __restrict__ deg, int* __restrict__ bsum, int n) {
    __shared__ int s[256];
    int t = threadIdx.x;
    int i = blockIdx.x * 256 + t;
    s[t] = (i < n) ? deg[i] : 0;
    __syncthreads();
    for (int off = 128; off > 0; off >>= 1) {
        if (t < off) s[t] += s[t + off];
        __syncthreads();
    }
    if (t == 0) bsum[blockIdx.x] = s[0];
}

__global__ void scan_mid_k(const int* __restrict__ bsum, int* __restrict__ boff,
                           int nblk, int* __restrict__ roff, int n) {
    __shared__ int s[512];
    int t = threadIdx.x;
    int v = (t < nblk) ? bsum[t] : 0;
    s[t] = v;
    __syncthreads();
    for (int off = 1; off < 512; off <<= 1) {
        int u = (t >= off) ? s[t - off] : 0;
        __syncthreads();
        s[t] += u;
        __syncthreads();
    }
    if (t < nblk) boff[t] = s[t] - v;          // exclusive
    if (t == nblk - 1) roff[n] = s[t];         // == E
}

__global__ void scan_final_k(const int* __restrict__ deg, const int* __restrict__ boff,
                             int* __restrict__ roff, int n) {
    __shared__ int s[256];
    int t = threadIdx.x;
    int i = blockIdx.x * 256 + t;
    int v = (i < n) ? deg[i] : 0;
    s[t] = v;
    __syncthreads();
    for (int off = 1; off < 256; off <<= 1) {
        int u = (t >= off) ? s[t - off] : 0;
        __syncthreads();
        s[t] += u;
        __syncthreads();
    }
    if (i < n) roff[i] = boff[blockIdx.x] + s[t] - v;   // exclusive scan
}

__global__ void fill_k(const int* __restrict__ src, const int* __restrict__ dst,
                       const int* __restrict__ roff, int* __restrict__ cursor,
                       int* __restrict__ csr, int E) {
    int e = blockIdx.x * blockDim.x + threadIdx.x;
    if (e < E) {
        int d = dst[e];
        int k = atomicAdd(&cursor[d], 1);
        csr[roff[d] + k] = src[e];
    }
}

__global__ void init_pool_k(unsigned* __restrict__ pooled, int total) {
    int i = blockIdx.x * blockDim.x + threadIdx.x;
    if (i < total) pooled[i] = 0x007FFFFFu;   // enc(-inf)
}

// ---------- fused GCN2 layer: agg + residual + GEMM + relu ----------
// One wave per node. W column held in 64 VGPRs (lane j holds W[:,j]).
// h-row exchanged via per-wave LDS slot, read back as broadcast float4.
__global__ __launch_bounds__(256, 4) void layer_k(
    const float* __restrict__ xin, float* __restrict__ xout,
    const float* __restrict__ x0, const float* __restrict__ W,
    const int* __restrict__ roff, const int* __restrict__ csr,
    float beta, int total_waves) {
    __shared__ __align__(16) float hrow[4][64];
    const int lane  = threadIdx.x & 63;
    const int wslot = threadIdx.x >> 6;
    const int wid0  = (blockIdx.x * blockDim.x + threadIdx.x) >> 6;
    float wcol[64];
#pragma unroll
    for (int k = 0; k < 64; ++k) wcol[k] = W[k * 64 + lane];
    const float omb = 1.0f - beta;
    for (int n = wid0; n < NNODES; n += total_waves) {
        const int beg = roff[n], end = roff[n + 1];
        float agg = 0.0f;
        int i = beg;
        for (; i + 4 <= end; i += 4) {
            int s0 = csr[i + 0], s1 = csr[i + 1], s2 = csr[i + 2], s3 = csr[i + 3];
            float a0 = xin[(s0 << 6) + lane];
            float a1 = xin[(s1 << 6) + lane];
            float a2 = xin[(s2 << 6) + lane];
            float a3 = xin[(s3 << 6) + lane];
            agg += a0; agg += a1; agg += a2; agg += a3;
        }
        for (; i < end; ++i) {
            int s = csr[i];
            agg += xin[(s << 6) + lane];
        }
        float h = fmaf(0.9f, agg, 0.1f * x0[(n << 6) + lane]);
        hrow[wslot][lane] = h;
        __builtin_amdgcn_wave_barrier();   // wave-internal LDS RAW; DS is in-order per wave
        float acc = 0.0f;
#pragma unroll
        for (int g = 0; g < 16; ++g) {
            float4 hv = *(const float4*)&hrow[wslot][g * 4];
            acc = fmaf(hv.x, wcol[4 * g + 0], acc);
            acc = fmaf(hv.y, wcol[4 * g + 1], acc);
            acc = fmaf(hv.z, wcol[4 * g + 2], acc);
            acc = fmaf(hv.w, wcol[4 * g + 3], acc);
        }
        __builtin_amdgcn_wave_barrier();   // keep next iter's write after these reads
        float o = fmaf(omb, h, beta * acc);
        xout[(n << 6) + lane] = fmaxf(o, 0.0f);
    }
}

// ---------- lin1 + segment_max pooling fused ----------
__global__ __launch_bounds__(256, 4) void lin1pool_k(
    const float* __restrict__ xin, const float* __restrict__ W,
    const float* __restrict__ bvec, const int* __restrict__ batch,
    unsigned* __restrict__ pooled, int total_waves) {
    __shared__ __align__(16) float hrow[4][64];
    const int lane  = threadIdx.x & 63;
    const int wslot = threadIdx.x >> 6;
    const int wid0  = (blockIdx.x * blockDim.x + threadIdx.x) >> 6;
    float wcol[64];
#pragma unroll
    for (int k = 0; k < 64; ++k) wcol[k] = W[k * 64 + lane];
    const float bias = bvec[lane];
    for (int n = wid0; n < NNODES; n += total_waves) {
        float xv = xin[(n << 6) + lane];
        hrow[wslot][lane] = xv;
        __builtin_amdgcn_wave_barrier();
        float acc = bias;
#pragma unroll
        for (int g = 0; g < 16; ++g) {
            float4 hv = *(const float4*)&hrow[wslot][g * 4];
            acc = fmaf(hv.x, wcol[4 * g + 0], acc);
            acc = fmaf(hv.y, wcol[4 * g + 1], acc);
            acc = fmaf(hv.z, wcol[4 * g + 2], acc);
            acc = fmaf(hv.w, wcol[4 * g + 3], acc);
        }
        __builtin_amdgcn_wave_barrier();
        int gi = batch[n];
        atomicMax(&pooled[(gi << 6) + lane], enc_f(acc));
    }
}

// ---------- head: MLP + BN + out + log_softmax, single block ----------
__global__ __launch_bounds__(256) void head_k(
    const unsigned* __restrict__ pooled,
    const float* __restrict__ m1w, const float* __restrict__ m1b,
    const float* __restrict__ g1, const float* __restrict__ be1,
    const float* __restrict__ m2w, const float* __restrict__ m2b,
    const float* __restrict__ g2, const float* __restrict__ be2,
    const float* __restrict__ ow, const float* __restrict__ ob,
    float* __restrict__ out) {
    __shared__ float A[NGRAPH * 64];
    __shared__ float B[NGRAPH * 64];
    __shared__ float mu[64], rs[64];
    __shared__ float LG[NGRAPH * 10];
    int t = threadIdx.x;
    for (int i = t; i < NGRAPH * 64; i += 256) {
        float f = dec_f(pooled[i]);
        if (!isfinite(f)) f = 0.0f;   // empty-segment guard
        A[i] = f;
    }
    __syncthreads();
    // ---- mlp1 ----
    for (int i = t; i < NGRAPH * 64; i += 256) {
        int g = i >> 6, j = i & 63;
        float acc = m1b[j];
        for (int k = 0; k < 64; ++k) acc = fmaf(A[(g << 6) + k], m1w[k * 64 + j], acc);
        B[i] = acc;
    }
    __syncthreads();
    if (t < 64) {
        float sm = 0.0f, sq = 0.0f;
        for (int g = 0; g < NGRAPH; ++g) { float z = B[g * 64 + t]; sm += z; sq += z * z; }
        float m = sm * (1.0f / NGRAPH);
        float var = sq * (1.0f / NGRAPH) - m * m;
        mu[t] = m; rs[t] = rsqrtf(var + 1e-5f);
    }
    __syncthreads();
    for (int i = t; i < NGRAPH * 64; i += 256) {
        int j = i & 63;
        float z = fmaf((B[i] - mu[j]) * rs[j], g1[j], be1[j]);
        A[i] = fmaxf(z, 0.0f);
    }
    __syncthreads();
    // ---- mlp2 ----
    for (int i = t; i < NGRAPH * 64; i += 256) {
        int g = i >> 6, j = i & 63;
        float acc = m2b[j];
        for (int k = 0; k < 64; ++k) acc = fmaf(A[(g << 6) + k], m2w[k * 64 + j], acc);
        B[i] = acc;
    }
    __syncthreads();
    if (t < 64) {
        float sm = 0.0f, sq = 0.0f;
        for (int g = 0; g < NGRAPH; ++g) { float z = B[g * 64 + t]; sm += z; sq += z * z; }
        float m = sm * (1.0f / NGRAPH);
        float var = sq * (1.0f / NGRAPH) - m * m;
        mu[t] = m; rs[t] = rsqrtf(var + 1e-5f);
    }
    __syncthreads();
    for (int i = t; i < NGRAPH * 64; i += 256) {
        int j = i & 63;
        float z = fmaf((B[i] - mu[j]) * rs[j], g2[j], be2[j]);
        A[i] = fmaxf(z, 0.0f);
    }
    __syncthreads();
    // ---- out + log_softmax ----
    for (int i = t; i < NGRAPH * 10; i += 256) {
        int g = i / 10, j = i - g * 10;
        float acc = ob[j];
        for (int k = 0; k < 64; ++k) acc = fmaf(A[(g << 6) + k], ow[k * 10 + j], acc);
        LG[i] = acc;
    }
    __syncthreads();
    if (t < NGRAPH) {
        float m = -1e30f;
        for (int j = 0; j < 10; ++j) m = fmaxf(m, LG[t * 10 + j]);
        float s = 0.0f;
        for (int j = 0; j < 10; ++j) s += expf(LG[t * 10 + j] - m);
        float lse = m + logf(s);
        for (int j = 0; j < 10; ++j) out[t * 10 + j] = LG[t * 10 + j] - lse;
    }
}

extern "C" void kernel_launch(void* const* d_in, const int* in_sizes, int n_in,
                              void* d_out, int out_size, void* d_ws, size_t ws_size,
                              hipStream_t stream) {
    const float* pos   = (const float*)d_in[0];
    const int*   eidx  = (const int*)d_in[1];
    const int*   batch = (const int*)d_in[2];
    const float* l0w   = (const float*)d_in[3];
    const float* l0b   = (const float*)d_in[4];
    const float* cw    = (const float*)d_in[5];
    const float* l1w   = (const float*)d_in[6];
    const float* l1b   = (const float*)d_in[7];
    const float* m1w   = (const float*)d_in[8];
    const float* m1b   = (const float*)d_in[9];
    const float* g1    = (const float*)d_in[10];
    const float* b1    = (const float*)d_in[11];
    const float* m2w   = (const float*)d_in[12];
    const float* m2b   = (const float*)d_in[13];
    const float* g2    = (const float*)d_in[14];
    const float* b2    = (const float*)d_in[15];
    const float* ow    = (const float*)d_in[16];
    const float* ob    = (const float*)d_in[17];
    float* out = (float*)d_out;
    const int* src = eidx;
    const int* dst = eidx + NEDGES;

    size_t off = 0;
    auto alloc = [&](size_t bytes) -> void* {
        void* p = (char*)d_ws + off;
        off += (bytes + 255) & ~(size_t)255;
        return p;
    };
    float*    x0     = (float*)alloc((size_t)NNODES * 64 * 4);
    float*    xA     = (float*)alloc((size_t)NNODES * 64 * 4);
    float*    xB     = (float*)alloc((size_t)NNODES * 64 * 4);
    int*      deg    = (int*)alloc((size_t)NNODES * 4);          // reused as cursor
    int*      roff   = (int*)alloc((size_t)(NNODES + 1) * 4);
    const int NBLK   = (NNODES + 255) / 256;                     // 391
    int*      bsum   = (int*)alloc((size_t)NBLK * 4);
    int*      boff   = (int*)alloc((size_t)NBLK * 4);
    int*      csr    = (int*)alloc((size_t)NEDGES * 4);
    unsigned* pooled = (unsigned*)alloc((size_t)NGRAPH * 64 * 4);

    hipMemsetAsync(deg, 0, (size_t)NNODES * 4, stream);
    {
        int total = NNODES * 64;
        lin0_k<<<(total + 255) / 256, 256, 0, stream>>>(pos, l0w, l0b, x0, total);
    }
    hist_k<<<(NEDGES + 255) / 256, 256, 0, stream>>>(dst, deg, NEDGES);
    scan_part_k<<<NBLK, 256, 0, stream>>>(deg, bsum, NNODES);
    scan_mid_k<<<1, 512, 0, stream>>>(bsum, boff, NBLK, roff, NNODES);
    scan_final_k<<<NBLK, 256, 0, stream>>>(deg, boff, roff, NNODES);
    hipMemsetAsync(deg, 0, (size_t)NNODES * 4, stream);          // now cursor
    fill_k<<<(NEDGES + 255) / 256, 256, 0, stream>>>(src, dst, roff, deg, csr, NEDGES);
    init_pool_k<<<(NGRAPH * 64 + 255) / 256, 256, 0, stream>>>(pooled, NGRAPH * 64);

    const int LBLOCKS = 1024;
    const int TW = LBLOCKS * 256 / 64;   // total waves
    const float* cur = x0;
    for (int l = 0; l < NLAYERS; ++l) {
        float beta = (float)log(0.5 / (double)(l + 1) + 1.0);
        float* nxt = (l & 1) ? xB : xA;
        layer_k<<<LBLOCKS, 256, 0, stream>>>(cur, nxt, x0, cw + (size_t)l * 4096,
                                             roff, csr, beta, TW);
        cur = nxt;
    }
    lin1pool_k<<<LBLOCKS, 256, 0, stream>>>(cur, l1w, l1b, batch, pooled, TW);
    head_k<<<1, 256, 0, stream>>>(pooled, m1w, m1b, g1, b1, m2w, m2b, g2, b2, ow, ob, out);
}